// Round 1
// baseline (9004.009 us; speedup 1.0000x reference)
//
#include <hip/hip_runtime.h>
#include <hip/hip_bf16.h>
#include <math.h>

// dims
constexpr int B_ = 64, S_ = 512, LP_ = 18, CE_ = 10, LC_ = 16, LF_ = 32;
constexpr int WE_ = 200, H_ = 200, T_ = 64;
constexpr int N_ = B_ * S_;        // 32768 tokens, n = b*S + s = t*64 + j
constexpr int DIN_ = WE_ + LF_;    // 232
constexpr int G4_ = 4 * H_;        // 800

// ---------------- K1: char CNN + embeddings -> X [N, 232] ----------------
__global__ __launch_bounds__(256) void k_build_x(
    const int* __restrict__ char_ids, const int* __restrict__ word_ids,
    const float* __restrict__ word_emb, const float* __restrict__ char_emb,
    const float* __restrict__ conv_w, const float* __restrict__ conv_b,
    float* __restrict__ X)
{
  __shared__ float ce[4][LP_ * CE_];           // 4 tokens per block, 180 floats each
  const int wave = threadIdx.x >> 6, lane = threadIdx.x & 63;
  const int n = blockIdx.x * 4 + wave;

  // gather char embeddings for this token
  for (int i = lane; i < LP_ * CE_; i += 64) {
    int c = char_ids[n * LP_ + i / CE_];
    ce[wave][i] = char_emb[c * CE_ + (i % CE_)];
  }
  // word embedding copy (independent of LDS)
  const float* we = word_emb + (size_t)word_ids[n] * WE_;
  for (int i = lane; i < WE_; i += 64) X[(size_t)n * DIN_ + i] = we[i];
  __syncthreads();

  // conv: lane -> (filter f, window-half). windows w use ce[w*10 .. w*10+29]
  const int f = lane & 31, half = lane >> 5;
  float cw[30];
  #pragma unroll
  for (int i = 0; i < 30; ++i) cw[i] = conv_w[f * 30 + i];
  float m = -1e30f;
  for (int w = half * 8; w < half * 8 + 8; ++w) {
    float acc = 0.f;
    #pragma unroll
    for (int i = 0; i < 30; ++i) acc += ce[wave][w * CE_ + i] * cw[i];
    m = fmaxf(m, acc);
  }
  m = fmaxf(m, __shfl_xor(m, 32));
  if (half == 0) X[(size_t)n * DIN_ + WE_ + f] = m + conv_b[f];
}

// ---------------- K2: G = X @ w_ih^T + (b_ih + b_hh), stored bf16 ----------------
__global__ __launch_bounds__(256) void k_proj(
    const float* __restrict__ X,
    const float* __restrict__ w_ih, const float* __restrict__ b_ih,
    const float* __restrict__ b_hh, __hip_bfloat16* __restrict__ G)
{
  __shared__ float xt[32 * DIN_];
  const int base = blockIdx.x * 32;
  for (int i = threadIdx.x; i < 32 * DIN_; i += 256)
    xt[i] = X[(size_t)base * DIN_ + i];
  __syncthreads();

  const int m = threadIdx.x >> 3, r0 = threadIdx.x & 7;
  const float4* xr = (const float4*)(xt + m * DIN_);
  const size_t outbase = (size_t)(base + m) * G4_;
  for (int r = r0; r < G4_; r += 8) {
    const float4* wr = (const float4*)(w_ih + (size_t)r * DIN_);
    float acc = b_ih[r] + b_hh[r];
    #pragma unroll
    for (int k = 0; k < DIN_ / 4; ++k) {
      float4 a = xr[k], w = wr[k];
      acc += a.x * w.x + a.y * w.y + a.z * w.z + a.w * w.w;
    }
    G[outbase + r] = __float2bfloat16(acc);
  }
}

// ---------------- K3: bidirectional LSTM recurrence, 2 chains per WG ----------------
__global__ __launch_bounds__(512) void k_lstm(
    const __hip_bfloat16* __restrict__ Gf, const __hip_bfloat16* __restrict__ Gb,
    const float* __restrict__ w_hh_f, const float* __restrict__ w_hh_b,
    float* __restrict__ hf, float* __restrict__ hb)
{
  __shared__ float h[2][H_], c[2][H_], g[2][G4_];
  const int dir = blockIdx.x >> 5;     // 32 blocks fwd, 32 bwd
  const int p = blockIdx.x & 31;       // chain pair -> j = 2p, 2p+1
  const __hip_bfloat16* G = dir ? Gb : Gf;
  const float* Whh = dir ? w_hh_b : w_hh_f;
  float* hout = dir ? hb : hf;

  for (int i = threadIdx.x; i < 2 * H_; i += 512) { (&h[0][0])[i] = 0.f; (&c[0][0])[i] = 0.f; }
  __syncthreads();

  for (int t = 0; t < S_; ++t) {
    const int step = dir ? (S_ - 1 - t) : t;
    const int n0 = step * 64 + p * 2;
    const __hip_bfloat16* g0 = G + (size_t)n0 * G4_;

    // gates = G + h @ w_hh^T for both chains (weight row reused for both)
    for (int r = threadIdx.x; r < G4_; r += 512) {
      const float4* wr = (const float4*)(Whh + (size_t)r * H_);
      const float4* h0 = (const float4*)h[0];
      const float4* h1 = (const float4*)h[1];
      float a0 = __bfloat162float(g0[r]);
      float a1 = __bfloat162float(g0[G4_ + r]);
      #pragma unroll 5
      for (int k = 0; k < H_ / 4; ++k) {
        float4 w = wr[k];
        float4 x0 = h0[k], x1 = h1[k];
        a0 += x0.x * w.x + x0.y * w.y + x0.z * w.z + x0.w * w.w;
        a1 += x1.x * w.x + x1.y * w.y + x1.z * w.z + x1.w * w.w;
      }
      g[0][r] = a0; g[1][r] = a1;
    }
    __syncthreads();

    if (threadIdx.x < 2 * H_) {
      const int ch = threadIdx.x / H_, u = threadIdx.x % H_;
      float gi = g[ch][u], gf = g[ch][H_ + u], gg = g[ch][2 * H_ + u], go = g[ch][3 * H_ + u];
      float si = 1.f / (1.f + __expf(-gi));
      float sf = 1.f / (1.f + __expf(-gf));
      float so = 1.f / (1.f + __expf(-go));
      float cn = sf * c[ch][u] + si * tanhf(gg);
      float hn = so * tanhf(cn);
      c[ch][u] = cn;
      h[ch][u] = hn;
      hout[(size_t)(n0 + ch) * H_ + u] = hn;
    }
    __syncthreads();
  }
}

// ---------------- K4: tag = [hf|hb] @ out_w^T + out_b ----------------
__global__ __launch_bounds__(256) void k_out(
    const float* __restrict__ hf, const float* __restrict__ hb,
    const float* __restrict__ out_w, const float* __restrict__ out_b,
    float* __restrict__ tag)
{
  const int m = threadIdx.x >> 3;   // token within block (0..31)
  const int tg = threadIdx.x & 7;   // tag group: tags tg + 8q
  const int n = blockIdx.x * 32 + m;
  const float4* hf4 = (const float4*)(hf + (size_t)n * H_);
  const float4* hb4 = (const float4*)(hb + (size_t)n * H_);
  float acc[8];
  #pragma unroll
  for (int q = 0; q < 8; ++q) acc[q] = out_b[tg + 8 * q];
  for (int k = 0; k < H_ / 4; ++k) {
    float4 hv = hf4[k];
    #pragma unroll
    for (int q = 0; q < 8; ++q) {
      float4 w = ((const float4*)(out_w + (size_t)(tg + 8 * q) * 2 * H_))[k];
      acc[q] += hv.x * w.x + hv.y * w.y + hv.z * w.z + hv.w * w.w;
    }
  }
  for (int k = 0; k < H_ / 4; ++k) {
    float4 hv = hb4[k];
    #pragma unroll
    for (int q = 0; q < 8; ++q) {
      float4 w = ((const float4*)(out_w + (size_t)(tg + 8 * q) * 2 * H_ + H_))[k];
      acc[q] += hv.x * w.x + hv.y * w.y + hv.z * w.z + hv.w * w.w;
    }
  }
  #pragma unroll
  for (int q = 0; q < 8; ++q) tag[(size_t)n * T_ + tg + 8 * q] = acc[q];
}

// ---------------- K5: log_softmax over the sequence axis (dim=1) ----------------
__global__ __launch_bounds__(256) void k_lsm(
    const float* __restrict__ tag, float* __restrict__ out)
{
  __shared__ float red[4][T_];
  __shared__ float lse[T_];
  const int b = blockIdx.x;
  const int tt = threadIdx.x & 63, ch = threadIdx.x >> 6;
  const float* tb = tag + (size_t)b * S_ * T_;

  float m = -1e30f;
  for (int s = ch * 128; s < ch * 128 + 128; ++s) m = fmaxf(m, tb[s * T_ + tt]);
  red[ch][tt] = m;
  __syncthreads();
  if (ch == 0)
    lse[tt] = fmaxf(fmaxf(red[0][tt], red[1][tt]), fmaxf(red[2][tt], red[3][tt]));
  __syncthreads();
  m = lse[tt];
  float sum = 0.f;
  for (int s = ch * 128; s < ch * 128 + 128; ++s) sum += __expf(tb[s * T_ + tt] - m);
  __syncthreads();   // ensure lse reads done before red reuse ordering below
  red[ch][tt] = sum;
  __syncthreads();
  if (ch == 0)
    lse[tt] = m + logf(red[0][tt] + red[1][tt] + red[2][tt] + red[3][tt]);
  __syncthreads();
  const float l = lse[tt];
  float* ob = out + (size_t)b * S_ * T_;
  for (int s = ch * 128; s < ch * 128 + 128; ++s) ob[s * T_ + tt] = tb[s * T_ + tt] - l;
}

// ---------------- launch ----------------
extern "C" void kernel_launch(void* const* d_in, const int* in_sizes, int n_in,
                              void* d_out, int out_size, void* d_ws, size_t ws_size,
                              hipStream_t stream) {
  const int*   char_ids = (const int*)d_in[0];
  const int*   word_ids = (const int*)d_in[1];
  const float* word_emb = (const float*)d_in[2];
  const float* char_emb = (const float*)d_in[3];
  const float* conv_w   = (const float*)d_in[4];
  const float* conv_b   = (const float*)d_in[5];
  const float* w_ih_f   = (const float*)d_in[6];
  const float* w_hh_f   = (const float*)d_in[7];
  const float* b_ih_f   = (const float*)d_in[8];
  const float* b_hh_f   = (const float*)d_in[9];
  const float* w_ih_b   = (const float*)d_in[10];
  const float* w_hh_b   = (const float*)d_in[11];
  const float* b_ih_b   = (const float*)d_in[12];
  const float* b_hh_b   = (const float*)d_in[13];
  const float* out_w    = (const float*)d_in[14];
  const float* out_b    = (const float*)d_in[15];

  // ws layout (bytes): X f32 | Gf bf16 | Gb bf16 | hf f32 | hb f32 | tag f32
  char* ws = (char*)d_ws;
  float*          X   = (float*)(ws);                        // 30,408,704
  __hip_bfloat16* Gf  = (__hip_bfloat16*)(ws + 30408704);    // 52,428,800
  __hip_bfloat16* Gb  = (__hip_bfloat16*)(ws + 82837504);    // 52,428,800
  float*          hf  = (float*)(ws + 135266304);            // 26,214,400
  float*          hb  = (float*)(ws + 161480704);            // 26,214,400
  float*          tag = (float*)(ws + 187695104);            // 8,388,608  -> total 196,083,712

  hipLaunchKernelGGL(k_build_x, dim3(N_ / 4), dim3(256), 0, stream,
                     char_ids, word_ids, word_emb, char_emb, conv_w, conv_b, X);
  hipLaunchKernelGGL(k_proj, dim3(N_ / 32), dim3(256), 0, stream, X, w_ih_f, b_ih_f, b_hh_f, Gf);
  hipLaunchKernelGGL(k_proj, dim3(N_ / 32), dim3(256), 0, stream, X, w_ih_b, b_ih_b, b_hh_b, Gb);
  hipLaunchKernelGGL(k_lstm, dim3(64), dim3(512), 0, stream, Gf, Gb, w_hh_f, w_hh_b, hf, hb);
  hipLaunchKernelGGL(k_out, dim3(N_ / 32), dim3(256), 0, stream, hf, hb, out_w, out_b, tag);
  hipLaunchKernelGGL(k_lsm, dim3(B_), dim3(256), 0, stream, tag, (float*)d_out);
}

// Round 2
// 3217.936 us; speedup vs baseline: 2.7981x; 2.7981x over previous
//
#include <hip/hip_runtime.h>
#include <hip/hip_bf16.h>
#include <math.h>

// dims
constexpr int B_ = 64, S_ = 512, LP_ = 18, CE_ = 10, LF_ = 32;
constexpr int WE_ = 200, H_ = 200, T_ = 64;
constexpr int N_ = B_ * S_;        // 32768 tokens, n = b*S + s = t*64 + j
constexpr int KP_ = 256;           // padded K for GEMM (232 -> 256)
constexpr int G4_ = 800;           // 4*H
constexpr int NG_ = 1600;          // both directions stacked

typedef short short8 __attribute__((ext_vector_type(8)));
typedef float f32x4 __attribute__((ext_vector_type(4)));

__device__ __forceinline__ ushort bf16bits(float v) {
  return __bfloat16_as_ushort(__float2bfloat16(v));
}
__device__ __forceinline__ float bf2f(ushort u) {
  return __uint_as_float(((uint)u) << 16);
}

// packed bf16x2 dot product: acc + lo*lo + hi*hi
__device__ __forceinline__ float dot2bf(uint w, uint h, float acc) {
#if defined(__has_builtin)
#if __has_builtin(__builtin_amdgcn_fdot2_f32_bf16)
  typedef __bf16 bf16x2 __attribute__((ext_vector_type(2)));
  union U { uint u; bf16x2 v; };
  U a, b; a.u = w; b.u = h;
  return __builtin_amdgcn_fdot2_f32_bf16(a.v, b.v, acc, false);
#else
  float wl = __uint_as_float(w << 16), wh = __uint_as_float(w & 0xffff0000u);
  float hl = __uint_as_float(h << 16), hh = __uint_as_float(h & 0xffff0000u);
  return acc + wl * hl + wh * hh;
#endif
#else
  float wl = __uint_as_float(w << 16), wh = __uint_as_float(w & 0xffff0000u);
  float hl = __uint_as_float(h << 16), hh = __uint_as_float(h & 0xffff0000u);
  return acc + wl * hl + wh * hh;
#endif
}

// ---------------- K1: char CNN + embeddings -> Xb [N, 256] bf16 (zero-padded) ----------------
__global__ __launch_bounds__(256) void k_build_x(
    const int* __restrict__ char_ids, const int* __restrict__ word_ids,
    const float* __restrict__ word_emb, const float* __restrict__ char_emb,
    const float* __restrict__ conv_w, const float* __restrict__ conv_b,
    ushort* __restrict__ Xb)
{
  __shared__ float ce[4][LP_ * CE_];
  const int wave = threadIdx.x >> 6, lane = threadIdx.x & 63;
  const int n = blockIdx.x * 4 + wave;

  for (int i = lane; i < LP_ * CE_; i += 64) {
    int c = char_ids[n * LP_ + i / CE_];
    ce[wave][i] = char_emb[c * CE_ + (i % CE_)];
  }
  const float* we = word_emb + (size_t)word_ids[n] * WE_;
  ushort* xr = Xb + (size_t)n * KP_;
  for (int i = lane; i < WE_; i += 64) xr[i] = bf16bits(we[i]);
  if (lane < KP_ - WE_ - LF_) xr[WE_ + LF_ + lane] = 0;   // pad cols 232..255
  __syncthreads();

  const int f = lane & 31, half = lane >> 5;
  float cw[30];
  #pragma unroll
  for (int i = 0; i < 30; ++i) cw[i] = conv_w[f * 30 + i];
  float m = -1e30f;
  for (int w = half * 8; w < half * 8 + 8; ++w) {
    float acc = 0.f;
    #pragma unroll
    for (int i = 0; i < 30; ++i) acc += ce[wave][w * CE_ + i] * cw[i];
    m = fmaxf(m, acc);
  }
  m = fmaxf(m, __shfl_xor(m, 32));
  if (half == 0) xr[WE_ + f] = bf16bits(m + conv_b[f]);
}

// ---------------- pack W_ih (both dirs) -> Wb [1600][256] bf16, biasc [1600] f32 ----------------
__global__ __launch_bounds__(64) void k_pack_w(
    const float* __restrict__ w_ih_f, const float* __restrict__ w_ih_b,
    const float* __restrict__ b_ih_f, const float* __restrict__ b_hh_f,
    const float* __restrict__ b_ih_b, const float* __restrict__ b_hh_b,
    ushort* __restrict__ Wb, float* __restrict__ biasc)
{
  const int r = blockIdx.x;  // 0..1599
  const float* src = r < G4_ ? w_ih_f + (size_t)r * 232 : w_ih_b + (size_t)(r - G4_) * 232;
  for (int c = threadIdx.x; c < KP_; c += 64)
    Wb[(size_t)r * KP_ + c] = (c < 232) ? bf16bits(src[c]) : (ushort)0;
  if (threadIdx.x == 0)
    biasc[r] = r < G4_ ? (b_ih_f[r] + b_hh_f[r]) : (b_ih_b[r - G4_] + b_hh_b[r - G4_]);
}

// ---------------- pack w_hh -> wTp[dir][25][1024 rows][4 uints] (bf16x2 over k) ----------------
__global__ __launch_bounds__(64) void k_pack_whh(
    const float* __restrict__ w_hh_f, const float* __restrict__ w_hh_b,
    uint* __restrict__ wTp)
{
  const int bid = blockIdx.x;          // 0..2047
  const int dir = bid >> 10, r = bid & 1023;
  const int kk = threadIdx.x;
  if (kk >= 25) return;
  uint o0 = 0, o1 = 0, o2 = 0, o3 = 0;
  if (r < G4_) {
    const float* src = (dir ? w_hh_b : w_hh_f) + (size_t)r * H_ + kk * 8;
    o0 = (uint)bf16bits(src[0]) | ((uint)bf16bits(src[1]) << 16);
    o1 = (uint)bf16bits(src[2]) | ((uint)bf16bits(src[3]) << 16);
    o2 = (uint)bf16bits(src[4]) | ((uint)bf16bits(src[5]) << 16);
    o3 = (uint)bf16bits(src[6]) | ((uint)bf16bits(src[7]) << 16);
  }
  uint* dst = wTp + ((size_t)(dir * 25 + kk) * 1024 + r) * 4;
  dst[0] = o0; dst[1] = o1; dst[2] = o2; dst[3] = o3;
}

// ---------------- K2: MFMA GEMM  Gc[n][1600] = Xb @ Wb^T + bias (bf16 out) ----------------
__global__ __launch_bounds__(256) void k_gemm_proj(
    const ushort* __restrict__ Xb, const ushort* __restrict__ Wb,
    const float* __restrict__ biasc, ushort* __restrict__ Gc)
{
  __shared__ __align__(16) char smem[65536];   // A: 0..32K (swz), B: 32K..64K (swz); C f32 aliases A
  const int tid = threadIdx.x;
  const int lane = tid & 63, w = tid >> 6;
  const int wr = w >> 1, wc = w & 1;
  const int rowbase = blockIdx.y * 64, colbase = blockIdx.x * 64;

  // stage A,B tiles (64 rows x 512B) with XOR swizzle: stored[row][c16] = glb[row][c16 ^ (row&7)]
  const char* Ag = (const char*)(Xb + (size_t)rowbase * KP_);
  const char* Bg = (const char*)(Wb + (size_t)colbase * KP_);
  #pragma unroll
  for (int it = 0; it < 8; ++it) {
    int slot = it * 256 + tid;
    int row = slot >> 5, c16 = slot & 31;
    int src = row * 512 + c16 * 16;
    int dst = row * 512 + ((c16 * 16) ^ ((row & 7) << 4));
    *(short8*)(smem + dst) = *(const short8*)(Ag + src);
    *(short8*)(smem + 32768 + dst) = *(const short8*)(Bg + src);
  }
  __syncthreads();

  f32x4 acc[2][2] = {};
  #pragma unroll
  for (int kk = 0; kk < 8; ++kk) {
    const int kb = kk * 64 + (lane >> 4) * 16;
    short8 a[2], b[2];
    #pragma unroll
    for (int m = 0; m < 2; ++m) {
      int ar = wr * 32 + m * 16 + (lane & 15);
      a[m] = *(const short8*)(smem + ar * 512 + (kb ^ ((ar & 7) << 4)));
      int bc = wc * 32 + m * 16 + (lane & 15);
      b[m] = *(const short8*)(smem + 32768 + bc * 512 + (kb ^ ((bc & 7) << 4)));
    }
    #pragma unroll
    for (int m = 0; m < 2; ++m)
      #pragma unroll
      for (int n = 0; n < 2; ++n)
        acc[m][n] = __builtin_amdgcn_mfma_f32_16x16x32_bf16(a[m], b[n], acc[m][n], 0, 0, 0);
  }
  __syncthreads();

  // dump acc -> Cs[64][65] f32 (aliases A region), then vectorized bf16 store
  float* Cs = (float*)smem;
  #pragma unroll
  for (int m = 0; m < 2; ++m)
    #pragma unroll
    for (int n = 0; n < 2; ++n)
      #pragma unroll
      for (int i = 0; i < 4; ++i) {
        int r = wr * 32 + m * 16 + (lane >> 4) * 4 + i;
        int c = wc * 32 + n * 16 + (lane & 15);
        Cs[r * 65 + c] = acc[m][n][i];
      }
  __syncthreads();

  const int r = tid >> 2, cg = (tid & 3) * 16;
  ushort ob[16];
  #pragma unroll
  for (int j = 0; j < 16; ++j)
    ob[j] = bf16bits(Cs[r * 65 + cg + j] + biasc[colbase + cg + j]);
  ushort* dst = Gc + (size_t)(rowbase + r) * NG_ + colbase + cg;
  *(short8*)(dst) = *(short8*)(ob);
  *(short8*)(dst + 8) = *(short8*)(ob + 8);
}

// ---------------- K3: LSTM recurrence, coalesced packed-bf16 weights ----------------
__global__ __launch_bounds__(512) void k_lstm(
    const ushort* __restrict__ Gc, const uint* __restrict__ wTp,
    float* __restrict__ hf, float* __restrict__ hb)
{
  __shared__ __align__(16) float g2[2][1024];
  __shared__ __align__(16) uint hpk[2][100];   // packed bf16 pairs of h (both chains)
  const int tid = threadIdx.x;
  const int dir = blockIdx.x >> 5, p = blockIdx.x & 31;   // chains 2p, 2p+1
  const uint* Wd = wTp + (size_t)dir * 25 * 1024 * 4;
  float* hout = dir ? hb : hf;
  const bool has1 = tid < G4_ - 512;   // second row r1 = tid+512 valid (tid<288)

  if (tid < 200) { ((uint*)hpk)[tid] = 0; }
  float creg = 0.f;
  __syncthreads();

  for (int t = 0; t < S_; ++t) {
    const int step = dir ? (S_ - 1 - t) : t;
    const int n0 = step * 64 + 2 * p;
    const ushort* gr = Gc + (size_t)n0 * NG_ + dir * G4_;

    // preact loads issued early (HBM latency overlaps the k-loop)
    float p_r0c0 = bf2f(gr[tid]);
    float p_r0c1 = bf2f(gr[NG_ + tid]);
    float p_r1c0 = 0.f, p_r1c1 = 0.f;
    if (has1) { p_r1c0 = bf2f(gr[tid + 512]); p_r1c1 = bf2f(gr[NG_ + tid + 512]); }

    float a_r0c0 = 0.f, a_r0c1 = 0.f, a_r1c0 = 0.f, a_r1c1 = 0.f;
    #pragma unroll 5
    for (int kk = 0; kk < 25; ++kk) {
      const uint4 h0 = *(const uint4*)&hpk[0][kk * 4];
      const uint4 h1 = *(const uint4*)&hpk[1][kk * 4];
      const uint4 w0 = *(const uint4*)(Wd + ((size_t)(kk * 1024 + tid) << 2));
      a_r0c0 = dot2bf(w0.x, h0.x, a_r0c0); a_r0c0 = dot2bf(w0.y, h0.y, a_r0c0);
      a_r0c0 = dot2bf(w0.z, h0.z, a_r0c0); a_r0c0 = dot2bf(w0.w, h0.w, a_r0c0);
      a_r0c1 = dot2bf(w0.x, h1.x, a_r0c1); a_r0c1 = dot2bf(w0.y, h1.y, a_r0c1);
      a_r0c1 = dot2bf(w0.z, h1.z, a_r0c1); a_r0c1 = dot2bf(w0.w, h1.w, a_r0c1);
      if (has1) {
        const uint4 w1 = *(const uint4*)(Wd + ((size_t)(kk * 1024 + tid + 512) << 2));
        a_r1c0 = dot2bf(w1.x, h0.x, a_r1c0); a_r1c0 = dot2bf(w1.y, h0.y, a_r1c0);
        a_r1c0 = dot2bf(w1.z, h0.z, a_r1c0); a_r1c0 = dot2bf(w1.w, h0.w, a_r1c0);
        a_r1c1 = dot2bf(w1.x, h1.x, a_r1c1); a_r1c1 = dot2bf(w1.y, h1.y, a_r1c1);
        a_r1c1 = dot2bf(w1.z, h1.z, a_r1c1); a_r1c1 = dot2bf(w1.w, h1.w, a_r1c1);
      }
    }
    g2[0][tid] = a_r0c0 + p_r0c0;
    g2[1][tid] = a_r0c1 + p_r0c1;
    if (has1) {
      g2[0][tid + 512] = a_r1c0 + p_r1c0;
      g2[1][tid + 512] = a_r1c1 + p_r1c1;
    }
    __syncthreads();

    if (tid < 400) {
      const int ch = (tid >= 200) ? 1 : 0;
      const int u = tid - ch * 200;
      float gi = g2[ch][u], gf_ = g2[ch][200 + u], gg = g2[ch][400 + u], go = g2[ch][600 + u];
      float si = 1.f / (1.f + __expf(-gi));
      float sf = 1.f / (1.f + __expf(-gf_));
      float so = 1.f / (1.f + __expf(-go));
      float cn = sf * creg + si * tanhf(gg);
      float hn = so * tanhf(cn);
      creg = cn;
      hout[(size_t)(n0 + ch) * H_ + u] = hn;
      uint hbits = (uint)bf16bits(hn);
      uint nbits = (uint)__shfl_xor((int)hbits, 1);
      if ((u & 1) == 0) hpk[ch][u >> 1] = hbits | (nbits << 16);
    }
    __syncthreads();
  }
}

// ---------------- K4: tag = [hf|hb] @ out_w^T + out_b ----------------
__global__ __launch_bounds__(256) void k_out(
    const float* __restrict__ hf, const float* __restrict__ hb,
    const float* __restrict__ out_w, const float* __restrict__ out_b,
    float* __restrict__ tag)
{
  const int m = threadIdx.x >> 3;
  const int tg = threadIdx.x & 7;
  const int n = blockIdx.x * 32 + m;
  const float4* hf4 = (const float4*)(hf + (size_t)n * H_);
  const float4* hb4 = (const float4*)(hb + (size_t)n * H_);
  float acc[8];
  #pragma unroll
  for (int q = 0; q < 8; ++q) acc[q] = out_b[tg + 8 * q];
  for (int k = 0; k < H_ / 4; ++k) {
    float4 hv = hf4[k];
    #pragma unroll
    for (int q = 0; q < 8; ++q) {
      float4 w = ((const float4*)(out_w + (size_t)(tg + 8 * q) * 2 * H_))[k];
      acc[q] += hv.x * w.x + hv.y * w.y + hv.z * w.z + hv.w * w.w;
    }
  }
  for (int k = 0; k < H_ / 4; ++k) {
    float4 hv = hb4[k];
    #pragma unroll
    for (int q = 0; q < 8; ++q) {
      float4 w = ((const float4*)(out_w + (size_t)(tg + 8 * q) * 2 * H_ + H_))[k];
      acc[q] += hv.x * w.x + hv.y * w.y + hv.z * w.z + hv.w * w.w;
    }
  }
  #pragma unroll
  for (int q = 0; q < 8; ++q) tag[(size_t)n * T_ + tg + 8 * q] = acc[q];
}

// ---------------- K5: log_softmax over the sequence axis (dim=1) ----------------
__global__ __launch_bounds__(256) void k_lsm(
    const float* __restrict__ tag, float* __restrict__ out)
{
  __shared__ float red[4][T_];
  __shared__ float lse[T_];
  const int b = blockIdx.x;
  const int tt = threadIdx.x & 63, ch = threadIdx.x >> 6;
  const float* tb = tag + (size_t)b * S_ * T_;

  float m = -1e30f;
  for (int s = ch * 128; s < ch * 128 + 128; ++s) m = fmaxf(m, tb[s * T_ + tt]);
  red[ch][tt] = m;
  __syncthreads();
  if (ch == 0)
    lse[tt] = fmaxf(fmaxf(red[0][tt], red[1][tt]), fmaxf(red[2][tt], red[3][tt]));
  __syncthreads();
  m = lse[tt];
  float sum = 0.f;
  for (int s = ch * 128; s < ch * 128 + 128; ++s) sum += __expf(tb[s * T_ + tt] - m);
  __syncthreads();
  red[ch][tt] = sum;
  __syncthreads();
  if (ch == 0)
    lse[tt] = m + logf(red[0][tt] + red[1][tt] + red[2][tt] + red[3][tt]);
  __syncthreads();
  const float l = lse[tt];
  float* ob = out + (size_t)b * S_ * T_;
  for (int s = ch * 128; s < ch * 128 + 128; ++s) ob[s * T_ + tt] = tb[s * T_ + tt] - l;
}

// ---------------- launch ----------------
extern "C" void kernel_launch(void* const* d_in, const int* in_sizes, int n_in,
                              void* d_out, int out_size, void* d_ws, size_t ws_size,
                              hipStream_t stream) {
  const int*   char_ids = (const int*)d_in[0];
  const int*   word_ids = (const int*)d_in[1];
  const float* word_emb = (const float*)d_in[2];
  const float* char_emb = (const float*)d_in[3];
  const float* conv_w   = (const float*)d_in[4];
  const float* conv_b   = (const float*)d_in[5];
  const float* w_ih_f   = (const float*)d_in[6];
  const float* w_hh_f   = (const float*)d_in[7];
  const float* b_ih_f   = (const float*)d_in[8];
  const float* b_hh_f   = (const float*)d_in[9];
  const float* w_ih_b   = (const float*)d_in[10];
  const float* w_hh_b   = (const float*)d_in[11];
  const float* b_ih_b   = (const float*)d_in[12];
  const float* b_hh_b   = (const float*)d_in[13];
  const float* out_w    = (const float*)d_in[14];
  const float* out_b    = (const float*)d_in[15];

  // ws layout (bytes)
  char* ws = (char*)d_ws;
  ushort* Xb    = (ushort*)(ws);                 // 16,777,216  [32768][256] bf16
  ushort* Wb    = (ushort*)(ws + 16777216);      //    819,200  [1600][256] bf16
  float*  biasc = (float*) (ws + 17596416);      //      6,400  [1600] f32
  uint*   wTp   = (uint*)  (ws + 17602816);      //    819,200  [2][25][1024][4] uint
  ushort* Gc    = (ushort*)(ws + 18422016);      // 104,857,600 [32768][1600] bf16
  float*  hf    = (float*) (ws + 123279616);     // 26,214,400
  float*  hb    = (float*) (ws + 149494016);     // 26,214,400
  float*  tag   = (float*) (ws + 175708416);     //  8,388,608  -> total 184,097,024

  hipLaunchKernelGGL(k_build_x, dim3(N_ / 4), dim3(256), 0, stream,
                     char_ids, word_ids, word_emb, char_emb, conv_w, conv_b, Xb);
  hipLaunchKernelGGL(k_pack_w, dim3(NG_), dim3(64), 0, stream,
                     w_ih_f, w_ih_b, b_ih_f, b_hh_f, b_ih_b, b_hh_b, Wb, biasc);
  hipLaunchKernelGGL(k_pack_whh, dim3(2048), dim3(64), 0, stream, w_hh_f, w_hh_b, wTp);
  hipLaunchKernelGGL(k_gemm_proj, dim3(NG_ / 64, N_ / 64), dim3(256), 0, stream,
                     Xb, Wb, biasc, Gc);
  hipLaunchKernelGGL(k_lstm, dim3(64), dim3(512), 0, stream, Gc, wTp, hf, hb);
  hipLaunchKernelGGL(k_out, dim3(N_ / 32), dim3(256), 0, stream, hf, hb, out_w, out_b, tag);
  hipLaunchKernelGGL(k_lsm, dim3(B_), dim3(256), 0, stream, tag, (float*)d_out);
}

// Round 3
// 2571.431 us; speedup vs baseline: 3.5016x; 1.2514x over previous
//
#include <hip/hip_runtime.h>
#include <hip/hip_bf16.h>
#include <math.h>

// dims
constexpr int B_ = 64, S_ = 512, LP_ = 18, CE_ = 10, LF_ = 32;
constexpr int WE_ = 200, H_ = 200, T_ = 64;
constexpr int N_ = B_ * S_;        // 32768 tokens, n = b*S + s = t*64 + j
constexpr int KP_ = 256;           // padded K for proj GEMM (232 -> 256)
constexpr int G4_ = 800;           // 4*H
constexpr int NG_ = 1600;          // both directions stacked

typedef short short8 __attribute__((ext_vector_type(8)));
typedef float f32x4 __attribute__((ext_vector_type(4)));

__device__ __forceinline__ ushort bf16bits(float v) {
  return __bfloat16_as_ushort(__float2bfloat16(v));
}
__device__ __forceinline__ float bf2f(ushort u) {
  return __uint_as_float(((uint)u) << 16);
}
__device__ __forceinline__ float sigf(float x) {
  return 1.f / (1.f + __expf(-x));
}
__device__ __forceinline__ float tanhfast(float x) {
  // tanh(x) = 2*sigmoid(2x) - 1 ; saturates correctly for |x| large
  return 2.f / (1.f + __expf(-2.f * x)) - 1.f;
}

// ---------------- K1: char CNN + embeddings -> Xb [N, 256] bf16 (zero-padded) ----------------
__global__ __launch_bounds__(256) void k_build_x(
    const int* __restrict__ char_ids, const int* __restrict__ word_ids,
    const float* __restrict__ word_emb, const float* __restrict__ char_emb,
    const float* __restrict__ conv_w, const float* __restrict__ conv_b,
    ushort* __restrict__ Xb)
{
  __shared__ float ce[4][LP_ * CE_];
  const int wave = threadIdx.x >> 6, lane = threadIdx.x & 63;
  const int n = blockIdx.x * 4 + wave;

  for (int i = lane; i < LP_ * CE_; i += 64) {
    int c = char_ids[n * LP_ + i / CE_];
    ce[wave][i] = char_emb[c * CE_ + (i % CE_)];
  }
  const float* we = word_emb + (size_t)word_ids[n] * WE_;
  ushort* xr = Xb + (size_t)n * KP_;
  for (int i = lane; i < WE_; i += 64) xr[i] = bf16bits(we[i]);
  if (lane < KP_ - WE_ - LF_) xr[WE_ + LF_ + lane] = 0;   // pad cols 232..255
  __syncthreads();

  const int f = lane & 31, half = lane >> 5;
  float cw[30];
  #pragma unroll
  for (int i = 0; i < 30; ++i) cw[i] = conv_w[f * 30 + i];
  float m = -1e30f;
  for (int w = half * 8; w < half * 8 + 8; ++w) {
    float acc = 0.f;
    #pragma unroll
    for (int i = 0; i < 30; ++i) acc += ce[wave][w * CE_ + i] * cw[i];
    m = fmaxf(m, acc);
  }
  m = fmaxf(m, __shfl_xor(m, 32));
  if (half == 0) xr[WE_ + f] = bf16bits(m + conv_b[f]);
}

// ---------------- pack W_ih (both dirs) -> Wb [1600][256] bf16, biasc [1600] f32 ----------------
__global__ __launch_bounds__(64) void k_pack_w(
    const float* __restrict__ w_ih_f, const float* __restrict__ w_ih_b,
    const float* __restrict__ b_ih_f, const float* __restrict__ b_hh_f,
    const float* __restrict__ b_ih_b, const float* __restrict__ b_hh_b,
    ushort* __restrict__ Wb, float* __restrict__ biasc)
{
  const int r = blockIdx.x;  // 0..1599
  const float* src = r < G4_ ? w_ih_f + (size_t)r * 232 : w_ih_b + (size_t)(r - G4_) * 232;
  for (int c = threadIdx.x; c < KP_; c += 64)
    Wb[(size_t)r * KP_ + c] = (c < 232) ? bf16bits(src[c]) : (ushort)0;
  if (threadIdx.x == 0)
    biasc[r] = r < G4_ ? (b_ih_f[r] + b_hh_f[r]) : (b_ih_b[r - G4_] + b_hh_b[r - G4_]);
}

// ---------------- K2: MFMA GEMM  Gc[n][1600] = Xb @ Wb^T + bias (bf16 out) ----------------
__global__ __launch_bounds__(256) void k_gemm_proj(
    const ushort* __restrict__ Xb, const ushort* __restrict__ Wb,
    const float* __restrict__ biasc, ushort* __restrict__ Gc)
{
  __shared__ __align__(16) char smem[65536];
  const int tid = threadIdx.x;
  const int lane = tid & 63, w = tid >> 6;
  const int wr = w >> 1, wc = w & 1;
  const int rowbase = blockIdx.y * 64, colbase = blockIdx.x * 64;

  const char* Ag = (const char*)(Xb + (size_t)rowbase * KP_);
  const char* Bg = (const char*)(Wb + (size_t)colbase * KP_);
  #pragma unroll
  for (int it = 0; it < 8; ++it) {
    int slot = it * 256 + tid;
    int row = slot >> 5, c16 = slot & 31;
    int src = row * 512 + c16 * 16;
    int dst = row * 512 + ((c16 * 16) ^ ((row & 7) << 4));
    *(short8*)(smem + dst) = *(const short8*)(Ag + src);
    *(short8*)(smem + 32768 + dst) = *(const short8*)(Bg + src);
  }
  __syncthreads();

  f32x4 acc[2][2] = {};
  #pragma unroll
  for (int kk = 0; kk < 8; ++kk) {
    const int kb = kk * 64 + (lane >> 4) * 16;
    short8 a[2], b[2];
    #pragma unroll
    for (int m = 0; m < 2; ++m) {
      int ar = wr * 32 + m * 16 + (lane & 15);
      a[m] = *(const short8*)(smem + ar * 512 + (kb ^ ((ar & 7) << 4)));
      int bc = wc * 32 + m * 16 + (lane & 15);
      b[m] = *(const short8*)(smem + 32768 + bc * 512 + (kb ^ ((bc & 7) << 4)));
    }
    #pragma unroll
    for (int m = 0; m < 2; ++m)
      #pragma unroll
      for (int n = 0; n < 2; ++n)
        acc[m][n] = __builtin_amdgcn_mfma_f32_16x16x32_bf16(a[m], b[n], acc[m][n], 0, 0, 0);
  }
  __syncthreads();

  float* Cs = (float*)smem;
  #pragma unroll
  for (int m = 0; m < 2; ++m)
    #pragma unroll
    for (int n = 0; n < 2; ++n)
      #pragma unroll
      for (int i = 0; i < 4; ++i) {
        int r = wr * 32 + m * 16 + (lane >> 4) * 4 + i;
        int c = wc * 32 + n * 16 + (lane & 15);
        Cs[r * 65 + c] = acc[m][n][i];
      }
  __syncthreads();

  const int r = tid >> 2, cg = (tid & 3) * 16;
  ushort ob[16];
  #pragma unroll
  for (int j = 0; j < 16; ++j)
    ob[j] = bf16bits(Cs[r * 65 + cg + j] + biasc[colbase + cg + j]);
  ushort* dst = Gc + (size_t)(rowbase + r) * NG_ + colbase + cg;
  *(short8*)(dst) = *(short8*)(ob);
  *(short8*)(dst + 8) = *(short8*)(ob + 8);
}

// ---------------- K3: LSTM recurrence, weights resident in VGPRs + LDS ----------------
// 8 blocks = 2 dirs x 4 chain-groups(16). 512 thr = 8 waves.
// Unit slots: s=0..11: off=12s cnt=12 ; s=12..15: off=144+16(s-12) cnt=16 (slot15: 8 real).
// Wave w owns slots 2w, 2w+1; per slot 4 gate-tiles (16 rows x 224 k): k-tiles 0..4 in
// registers, k-tiles 5,6 in LDS (tile 6 only lanes hi==0 are nonzero -> 256B/group).
__global__ __launch_bounds__(512, 2) void k_lstm(
    const ushort* __restrict__ Gc,
    const float* __restrict__ w_hh_f, const float* __restrict__ w_hh_b,
    float* __restrict__ hf, float* __restrict__ hb)
{
  __shared__ ushort h_lds[16][232];                 // [chain][k] bf16, zero-padded k>=200
  __shared__ __align__(16) char wlds5[65536];       // k-tile 5 frags: gid*1024 + lane*16
  __shared__ __align__(16) char wlds6[16384];       // k-tile 6 frags: gid*256 + lo*16 (hi==0)

  const int tid = threadIdx.x;
  const int lane = tid & 63, w = tid >> 6;
  const int lo = lane & 15, hi = lane >> 4;
  const int dir = blockIdx.x >> 2, q = blockIdx.x & 3;
  const float* Whh = dir ? w_hh_b : w_hh_f;
  float* hout = dir ? hb : hf;

  for (int i = tid; i < 16 * 232; i += 512) ((ushort*)h_lds)[i] = 0;

  const int s0 = 2 * w, s1 = 2 * w + 1;
  const int off0 = s0 < 12 ? 12 * s0 : 144 + 16 * (s0 - 12);
  const int off1 = s1 < 12 ? 12 * s1 : 144 + 16 * (s1 - 12);
  const int cnt0 = s0 < 12 ? 12 : 16;
  const int cnt1 = s1 < 12 ? 12 : 16;
  const int rl0 = min(cnt0, 200 - off0);
  const int rl1 = min(cnt1, 200 - off1);
  const int offs[2] = {off0, off1};
  const int rls[2]  = {rl0, rl1};

  // ---- prologue: load weights into registers + LDS ----
  short8 wreg[2][4][5];
  #pragma unroll
  for (int sl = 0; sl < 2; ++sl) {
    const int off = offs[sl], rl = rls[sl];
    const bool rowok = lo < rl;
    const int s = 2 * w + sl;
    #pragma unroll
    for (int g = 0; g < 4; ++g) {
      const float* wr = Whh + (size_t)(g * 200 + off + lo) * 200;
      const int gid = s * 4 + g;
      #pragma unroll
      for (int kt = 0; kt < 7; ++kt) {
        const int k0 = kt * 32 + hi * 8;
        float v[8];
        if (rowok && k0 < 200) {
          float4 p0 = *(const float4*)(wr + k0);
          float4 p1 = *(const float4*)(wr + k0 + 4);
          v[0] = p0.x; v[1] = p0.y; v[2] = p0.z; v[3] = p0.w;
          v[4] = p1.x; v[5] = p1.y; v[6] = p1.z; v[7] = p1.w;
        } else {
          #pragma unroll
          for (int j = 0; j < 8; ++j) v[j] = 0.f;
        }
        short8 fr;
        #pragma unroll
        for (int j = 0; j < 8; ++j) fr[j] = (short)bf16bits(v[j]);
        if (kt < 5) wreg[sl][g][kt] = fr;
        else if (kt == 5) *(short8*)(wlds5 + gid * 1024 + lane * 16) = fr;
        else if (hi == 0) *(short8*)(wlds6 + gid * 256 + lo * 16) = fr;
      }
    }
  }
  __syncthreads();

  float c_[2][4] = {};
  const int jglob = q * 16 + lo;    // global chain

  for (int t = 0; t < S_; ++t) {
    const int step = dir ? (S_ - 1 - t) : t;
    const int n0 = step * 64 + q * 16;
    const ushort* gbase = Gc + (size_t)(n0 + lo) * NG_ + dir * G4_ + hi * 4;

    // preact loads, issued early
    uint2 pre[2][4];
    #pragma unroll
    for (int sl = 0; sl < 2; ++sl)
      #pragma unroll
      for (int g = 0; g < 4; ++g)
        pre[sl][g] = *(const uint2*)(gbase + g * 200 + offs[sl]);

    f32x4 acc[2][4] = {};
    const char* hrow = (const char*)h_lds + lo * 464 + hi * 16;
    #pragma unroll
    for (int kt = 0; kt < 7; ++kt) {
      short8 hfr = *(const short8*)(hrow + kt * 64);
      if (kt < 5) {
        #pragma unroll
        for (int sl = 0; sl < 2; ++sl)
          #pragma unroll
          for (int g = 0; g < 4; ++g)
            acc[sl][g] = __builtin_amdgcn_mfma_f32_16x16x32_bf16(
                wreg[sl][g][kt], hfr, acc[sl][g], 0, 0, 0);
      } else if (kt == 5) {
        #pragma unroll
        for (int sl = 0; sl < 2; ++sl)
          #pragma unroll
          for (int g = 0; g < 4; ++g) {
            const int gid = (2 * w + sl) * 4 + g;
            short8 wk = *(const short8*)(wlds5 + gid * 1024 + lane * 16);
            acc[sl][g] = __builtin_amdgcn_mfma_f32_16x16x32_bf16(wk, hfr, acc[sl][g], 0, 0, 0);
          }
      } else {
        #pragma unroll
        for (int sl = 0; sl < 2; ++sl)
          #pragma unroll
          for (int g = 0; g < 4; ++g) {
            const int gid = (2 * w + sl) * 4 + g;
            short8 wk = {};
            if (hi == 0) wk = *(const short8*)(wlds6 + gid * 256 + lo * 16);
            acc[sl][g] = __builtin_amdgcn_mfma_f32_16x16x32_bf16(wk, hfr, acc[sl][g], 0, 0, 0);
          }
      }
    }
    __syncthreads();   // all h_lds reads done before overwrites

    #pragma unroll
    for (int sl = 0; sl < 2; ++sl) {
      const int off = offs[sl], rl = rls[sl];
      float hv[4];
      #pragma unroll
      for (int i = 0; i < 4; ++i) {
        const uint2 pi = pre[sl][0], pf = pre[sl][1], pg = pre[sl][2], po = pre[sl][3];
        const uint wi = (i < 2) ? pi.x : pi.y;
        const uint wf = (i < 2) ? pf.x : pf.y;
        const uint wg = (i < 2) ? pg.x : pg.y;
        const uint wo = (i < 2) ? po.x : po.y;
        const int sh = (i & 1) * 16;
        float gi = acc[sl][0][i] + bf2f((ushort)(wi >> sh));
        float gf = acc[sl][1][i] + bf2f((ushort)(wf >> sh));
        float gg = acc[sl][2][i] + bf2f((ushort)(wg >> sh));
        float go = acc[sl][3][i] + bf2f((ushort)(wo >> sh));
        float cn = sigf(gf) * c_[sl][i] + sigf(gi) * tanhfast(gg);
        c_[sl][i] = cn;
        hv[i] = sigf(go) * tanhfast(cn);
      }
      const int u0 = off + hi * 4;
      if (hi * 4 < rl) {
        float4 o4 = make_float4(hv[0], hv[1], hv[2], hv[3]);
        *(float4*)(hout + (size_t)(n0 + lo) * H_ + u0) = o4;
        uint2 pk;
        pk.x = (uint)bf16bits(hv[0]) | ((uint)bf16bits(hv[1]) << 16);
        pk.y = (uint)bf16bits(hv[2]) | ((uint)bf16bits(hv[3]) << 16);
        *(uint2*)((char*)h_lds + lo * 464 + u0 * 2) = pk;
      }
    }
    __syncthreads();   // new h visible
  }
  (void)jglob;
}

// ---------------- K4: tag = [hf|hb] @ out_w^T + out_b ----------------
__global__ __launch_bounds__(256) void k_out(
    const float* __restrict__ hf, const float* __restrict__ hb,
    const float* __restrict__ out_w, const float* __restrict__ out_b,
    float* __restrict__ tag)
{
  const int m = threadIdx.x >> 3;
  const int tg = threadIdx.x & 7;
  const int n = blockIdx.x * 32 + m;
  const float4* hf4 = (const float4*)(hf + (size_t)n * H_);
  const float4* hb4 = (const float4*)(hb + (size_t)n * H_);
  float acc[8];
  #pragma unroll
  for (int q = 0; q < 8; ++q) acc[q] = out_b[tg + 8 * q];
  for (int k = 0; k < H_ / 4; ++k) {
    float4 hv = hf4[k];
    #pragma unroll
    for (int q = 0; q < 8; ++q) {
      float4 w = ((const float4*)(out_w + (size_t)(tg + 8 * q) * 2 * H_))[k];
      acc[q] += hv.x * w.x + hv.y * w.y + hv.z * w.z + hv.w * w.w;
    }
  }
  for (int k = 0; k < H_ / 4; ++k) {
    float4 hv = hb4[k];
    #pragma unroll
    for (int q = 0; q < 8; ++q) {
      float4 w = ((const float4*)(out_w + (size_t)(tg + 8 * q) * 2 * H_ + H_))[k];
      acc[q] += hv.x * w.x + hv.y * w.y + hv.z * w.z + hv.w * w.w;
    }
  }
  #pragma unroll
  for (int q = 0; q < 8; ++q) tag[(size_t)n * T_ + tg + 8 * q] = acc[q];
}

// ---------------- K5: log_softmax over the sequence axis (dim=1) ----------------
__global__ __launch_bounds__(256) void k_lsm(
    const float* __restrict__ tag, float* __restrict__ out)
{
  __shared__ float red[4][T_];
  __shared__ float lse[T_];
  const int b = blockIdx.x;
  const int tt = threadIdx.x & 63, ch = threadIdx.x >> 6;
  const float* tb = tag + (size_t)b * S_ * T_;

  float m = -1e30f;
  for (int s = ch * 128; s < ch * 128 + 128; ++s) m = fmaxf(m, tb[s * T_ + tt]);
  red[ch][tt] = m;
  __syncthreads();
  if (ch == 0)
    lse[tt] = fmaxf(fmaxf(red[0][tt], red[1][tt]), fmaxf(red[2][tt], red[3][tt]));
  __syncthreads();
  m = lse[tt];
  float sum = 0.f;
  for (int s = ch * 128; s < ch * 128 + 128; ++s) sum += __expf(tb[s * T_ + tt] - m);
  __syncthreads();
  red[ch][tt] = sum;
  __syncthreads();
  if (ch == 0)
    lse[tt] = m + logf(red[0][tt] + red[1][tt] + red[2][tt] + red[3][tt]);
  __syncthreads();
  const float l = lse[tt];
  float* ob = out + (size_t)b * S_ * T_;
  for (int s = ch * 128; s < ch * 128 + 128; ++s) ob[s * T_ + tt] = tb[s * T_ + tt] - l;
}

// ---------------- launch ----------------
extern "C" void kernel_launch(void* const* d_in, const int* in_sizes, int n_in,
                              void* d_out, int out_size, void* d_ws, size_t ws_size,
                              hipStream_t stream) {
  const int*   char_ids = (const int*)d_in[0];
  const int*   word_ids = (const int*)d_in[1];
  const float* word_emb = (const float*)d_in[2];
  const float* char_emb = (const float*)d_in[3];
  const float* conv_w   = (const float*)d_in[4];
  const float* conv_b   = (const float*)d_in[5];
  const float* w_ih_f   = (const float*)d_in[6];
  const float* w_hh_f   = (const float*)d_in[7];
  const float* b_ih_f   = (const float*)d_in[8];
  const float* b_hh_f   = (const float*)d_in[9];
  const float* w_ih_b   = (const float*)d_in[10];
  const float* w_hh_b   = (const float*)d_in[11];
  const float* b_ih_b   = (const float*)d_in[12];
  const float* b_hh_b   = (const float*)d_in[13];
  const float* out_w    = (const float*)d_in[14];
  const float* out_b    = (const float*)d_in[15];

  // ws layout (bytes)
  char* ws = (char*)d_ws;
  ushort* Xb    = (ushort*)(ws);                 // 16,777,216  [32768][256] bf16
  ushort* Wb    = (ushort*)(ws + 16777216);      //    819,200  [1600][256] bf16
  float*  biasc = (float*) (ws + 17596416);      //      6,400  [1600] f32
  ushort* Gc    = (ushort*)(ws + 18422016);      // 104,857,600 [32768][1600] bf16
  float*  hf    = (float*) (ws + 123279616);     // 26,214,400
  float*  hb    = (float*) (ws + 149494016);     // 26,214,400
  float*  tag   = (float*) (ws + 175708416);     //  8,388,608

  hipLaunchKernelGGL(k_build_x, dim3(N_ / 4), dim3(256), 0, stream,
                     char_ids, word_ids, word_emb, char_emb, conv_w, conv_b, Xb);
  hipLaunchKernelGGL(k_pack_w, dim3(NG_), dim3(64), 0, stream,
                     w_ih_f, w_ih_b, b_ih_f, b_hh_f, b_ih_b, b_hh_b, Wb, biasc);
  hipLaunchKernelGGL(k_gemm_proj, dim3(NG_ / 64, N_ / 64), dim3(256), 0, stream,
                     Xb, Wb, biasc, Gc);
  hipLaunchKernelGGL(k_lstm, dim3(8), dim3(512), 0, stream, Gc, w_hh_f, w_hh_b, hf, hb);
  hipLaunchKernelGGL(k_out, dim3(N_ / 32), dim3(256), 0, stream, hf, hb, out_w, out_b, tag);
  hipLaunchKernelGGL(k_lsm, dim3(B_), dim3(256), 0, stream, tag, (float*)d_out);
}